// Round 9
// baseline (247.910 us; speedup 1.0000x reference)
//
#include <hip/hip_runtime.h>

#define NPTS 131072
#define MNBR 34
#define KP 15
#define CIN 32
#define COUT 64
#define INV_INFL 25.0f          // 1 / POINT_INFLUENCE(0.04)
#define BN_EPS 1e-5f
#define NEG_SLOPE 0.2f
#define PPB 16                  // points per block (2 waves x 8)
#define NBLK (NPTS / PPB)       // 8192 conv blocks
#define NSB 512                 // stat blocks (256 points each)

typedef unsigned short u16;
typedef unsigned int u32;
typedef unsigned long long u64;
typedef short short8 __attribute__((ext_vector_type(8)));   // 8 bf16 (4 VGPRs)
typedef float f32x4 __attribute__((ext_vector_type(4)));

static __device__ __forceinline__ u16 f2bf(float f) {       // RNE
    u32 x = __float_as_uint(f);
    x += 0x7fffu + ((x >> 16) & 1u);
    return (u16)(x >> 16);
}
static __device__ __forceinline__ u32 pk2bf(float lo, float hi) {  // round-half-up pack
    u32 a = __float_as_uint(lo) + 0x8000u;
    u32 b = __float_as_uint(hi) + 0x8000u;
    return (a >> 16) | (b & 0xffff0000u);
}
static __device__ __forceinline__ u32 pkbf(float lo, float hi) {   // RNE pack (FB table)
    return (u32)f2bf(lo) | ((u32)f2bf(hi) << 16);
}

// ws layout (bytes) — total 10.38 MB (unchanged, proven footprint)
#define WS_WT   0u              // u16[64*480]          = 61440
#define WS_SCSH 65536u          // f32[128]
#define WS_CNT  66048u          // u32 completion counter for stat_bn
#define WS_PART 131072u         // f32[512*128]         = 262144 (block stat partials)
#define WS_XY   393216u         // float4[NPTS+1]       = 2097168 (xyz padded + shadow row)
#define WS_FB   2490624u        // u16[(NPTS+1)*32]     = 8388672 bf16 feats + zero shadow row

// prep: WT transpose, XY padded xyz table, FB bf16 table (uint4 fill), cnt=0
__global__ __launch_bounds__(256) void prep(const float* __restrict__ Wg,
                                            const float* __restrict__ feats,
                                            const float* __restrict__ xyz,
                                            u16* __restrict__ WT, float4* __restrict__ XY,
                                            uint4* __restrict__ FB4, u32* __restrict__ cnt) {
    int b = blockIdx.x;
    if (b == 0 && threadIdx.x == 0) *cnt = 0u;   // reset stat_bn election counter
    if (b < 120) {
        int i2 = b * 256 + threadIdx.x;          // < 30720
        WT[(i2 & 63) * 480 + (i2 >> 6)] = f2bf(Wg[i2]);
    } else if (b < 633) {
        int r = (b - 120) * 256 + threadIdx.x;
        if (r <= NPTS) {
            float4 v;
            if (r < NPTS) v = make_float4(xyz[3 * r], xyz[3 * r + 1], xyz[3 * r + 2], 0.f);
            else          v = make_float4(1e6f, 1e6f, 1e6f, 0.f);   // shadow -> w = 0
            XY[r] = v;
        }
    } else {
        // FB fill: one uint4 (8 bf16) per thread from two float4 loads.
        // real data: NPTS*CIN/8 = 524288 uint4; +4 uint4 shadow-row zeros.
        int g4 = (b - 633) * 256 + threadIdx.x;
        if (g4 < 524292) {
            uint4 v = make_uint4(0u, 0u, 0u, 0u);
            if (g4 < 524288) {
                const float4* F4 = (const float4*)feats;
                float4 f0 = F4[g4 * 2], f1 = F4[g4 * 2 + 1];
                v.x = pkbf(f0.x, f0.y); v.y = pkbf(f0.z, f0.w);
                v.z = pkbf(f1.x, f1.y); v.w = pkbf(f1.z, f1.w);
            }
            FB4[g4] = v;
        }
    }
}

__global__ __launch_bounds__(128, 3) void kpconv_conv(
    const float* __restrict__ xyz, const int* __restrict__ nbr,
    const float4* __restrict__ XY, const u32* __restrict__ FBu,
    const u16* __restrict__ WT, const float* __restrict__ kpts,
    float* __restrict__ out)
{
    // wf: 16 rows x 512 bf16; 16B-unit u of row r at phys (u ^ (r&7))   [R3-verified]
    __shared__ u32 wf[PPB * 256];            // 16 KB
    // offs: per-wave SINGLE-buffer (ox,oy,oz,|o|^2); slot m at phys
    // (m&~7)|((m^(m>>3))&7). Written+read within the same stage step.
    __shared__ float4 offs4[2][64];          // 2 KB     (total 18 KB)

    const int tid = threadIdx.x, lane = tid & 63, wave = tid >> 6;
    const int q = lane >> 4, t = lane & 15;
    const int pbase = blockIdx.x * PPB + wave * 8;

    // per-lane kernel-point constants (k == t only): d^2 = (o.a_t + c_t) + |o|^2
    float axt = 0.f, ayt = 0.f, azt = 0.f, ckt = 1e30f;   // t==15 pad -> w=0
    if (t < KP) {
        float kx = kpts[3 * t], ky = kpts[3 * t + 1], kz = kpts[3 * t + 2];
        axt = -2.f * kx; ayt = -2.f * ky; azt = -2.f * kz;
        ckt = fmaf(kx, kx, fmaf(ky, ky, kz * kz));
    }
    const int wslot = (lane & ~7) | ((lane ^ (lane >> 3)) & 7);
    const int sl = q * 8;                     // shuffle source base lane

    auto ldnbr = [&](int pp) {
        int v = NPTS;
        if (lane < MNBR) v = nbr[(size_t)(pbase + pp) * MNBR + lane];
        if ((u32)v > (u32)NPTS) v = NPTS;
        return v;
    };

    // hoisted wave-uniform query positions (compile-time indexed -> regs)
    float qxv[8], qyv[8], qzv[8];
    #pragma unroll
    for (int p = 0; p < 8; ++p) {
        const int n1 = pbase + p;
        qxv[p] = xyz[3 * n1]; qyv[p] = xyz[3 * n1 + 1]; qzv[p] = xyz[3 * n1 + 2];
    }

    // 3-deep pipeline: A = current point, B = +1, C = staged +2.
    // Weights computed AT STAGE TIME; per-row ballot of (w>0) gives an EXACT
    // skip mask (rows with all-zero weights contribute exactly 0; fb zero-init).
    u32 fbA[8] = {0,0,0,0,0,0,0,0};
    u32 fbB[8] = {0,0,0,0,0,0,0,0};
    u32 fbC[8] = {0,0,0,0,0,0,0,0};
    u32 d32A = 0, d33A = 0, d32B = 0, d33B = 0, d32C = 0, d33C = 0;
    u32 a1A[4], a1B[4], a1C[4];
    u32 a2A = 0, a2B = 0, a2C = 0;

    #define STAGE(P, ixP, pnP, a1X, a2X, fbX, d32X, d33X)                         \
    {                                                                              \
        float ox = (pnP).x - qxv[P], oy = (pnP).y - qyv[P], oz = (pnP).z - qzv[P]; \
        float ow = fmaf(ox, ox, fmaf(oy, oy, oz * oz));                            \
        offs4[wave][wslot] = make_float4(ox, oy, oz, ow);                          \
        const float4* ob = &offs4[wave][0];                                        \
        float wjs[8];                                                              \
        _Pragma("unroll")                                                          \
        for (int j = 0; j < 8; ++j) {                                              \
            float4 o = ob[q * 8 + (j ^ q)];    /* logical row q*8+j */             \
            float d2 = fmaf(o.x, axt, fmaf(o.y, ayt, fmaf(o.z, azt, ckt))) + o.w;  \
            float dd = __builtin_amdgcn_sqrtf(d2);                                 \
            wjs[j] = fmaxf(0.f, fmaf(dd, -INV_INFL, 1.f));                         \
        }                                                                          \
        _Pragma("unroll")                                                          \
        for (int i = 0; i < 4; ++i) a1X[i] = pk2bf(wjs[2 * i], wjs[2 * i + 1]);    \
        float4 oA = ob[36], oB = ob[37];       /* logical rows 32,33 */            \
        float dA = __builtin_amdgcn_sqrtf(fmaf(oA.x, axt, fmaf(oA.y, ayt, fmaf(oA.z, azt, ckt))) + oA.w); \
        float dB = __builtin_amdgcn_sqrtf(fmaf(oB.x, axt, fmaf(oB.y, ayt, fmaf(oB.z, azt, ckt))) + oB.w); \
        float wA = fmaxf(0.f, fmaf(dA, -INV_INFL, 1.f));                           \
        float wB = fmaxf(0.f, fmaf(dB, -INV_INFL, 1.f));                           \
        a2X = (q == 0) ? pk2bf(wA, wB) : 0u;                                       \
        _Pragma("unroll")                                                          \
        for (int j = 0; j < 8; ++j) {                                              \
            u64 bj = __ballot(wjs[j] > 0.f);   /* row q*8+j votes in [q*16,+16) */ \
            u32 half = (q & 2) ? (u32)(bj >> 32) : (u32)bj;                        \
            u32 m16 = (half >> ((q & 1) * 16)) & 0xffffu;                          \
            u32 r = (u32)__shfl((ixP), sl + j, 64);                                \
            if (m16) fbX[j] = FBu[(size_t)r * 16 + t];                             \
        }                                                                          \
        u64 b32 = __ballot(wA > 0.f);                                              \
        u64 b33 = __ballot(wB > 0.f);                                              \
        int r32 = __builtin_amdgcn_readlane((ixP), 32);                            \
        int r33 = __builtin_amdgcn_readlane((ixP), 33);                            \
        if (b32) d32X = FBu[(size_t)r32 * 16 + t];                                 \
        if (b33) d33X = FBu[(size_t)r33 * 16 + t];                                 \
    }

    // ---------------- prologue: nbr 0..3; XY 0..2; stage points 0 and 1
    int ix0 = ldnbr(0);
    int ix1 = ldnbr(1);
    int ixF = ldnbr(2);                       // stage source for p+2
    int ix3 = ldnbr(3);                       // XY load source for p+3
    float4 pn0 = XY[ix0];
    float4 pn1 = XY[ix1];
    float4 pnF = XY[ixF];

    STAGE(0, ix0, pn0, a1A, a2A, fbA, d32A, d33A);
    STAGE(1, ix1, pn1, a1B, a2B, fbB, d32B, d33B);

    // FULLY UNROLLED main loop.
    #pragma unroll
    for (int p = 0; p < 8; ++p) {
        // (a) nbr for p+4
        int ixN = NPTS;
        if (p < 4) ixN = ldnbr(p + 4);
        // (b) neighbor XY rows for p+3
        float4 pnN = make_float4(1e6f, 1e6f, 1e6f, 0.f);
        if (p < 5) pnN = XY[ix3];
        // (c) stage point p+2 (weights + exact-skip predicated gathers)
        if (p < 6) {
            STAGE(p + 2, ixF, pnF, a1C, a2C, fbC, d32C, d33C);
        }

        // (e) compute point p — everything from carried registers
        union { short8 v; u32 d[4]; } a1, a2, e1, o1u, e2, o2u;
        a1.d[0] = a1A[0]; a1.d[1] = a1A[1]; a1.d[2] = a1A[2]; a1.d[3] = a1A[3];
        a2.d[0] = a2A; a2.d[1] = 0; a2.d[2] = 0; a2.d[3] = 0;
        #pragma unroll
        for (int i = 0; i < 4; ++i) {                    // even/odd channel split
            u32 aa = fbA[2 * i], bb2 = fbA[2 * i + 1];
            e1.d[i] = (aa & 0xffffu) | (bb2 << 16);
            o1u.d[i] = (aa >> 16) | (bb2 & 0xffff0000u);
        }
        {
            u32 lo = (d32A & 0xffffu) | (d33A << 16);
            u32 hi = (d32A >> 16) | (d33A & 0xffff0000u);
            e2.d[0] = (q == 0) ? lo : 0u;  e2.d[1] = 0; e2.d[2] = 0; e2.d[3] = 0;
            o2u.d[0] = (q == 0) ? hi : 0u; o2u.d[1] = 0; o2u.d[2] = 0; o2u.d[3] = 0;
        }
        f32x4 c0 = {0.f, 0.f, 0.f, 0.f}, c1 = {0.f, 0.f, 0.f, 0.f};
        c0 = __builtin_amdgcn_mfma_f32_16x16x32_bf16(a1.v, e1.v, c0, 0, 0, 0);
        c0 = __builtin_amdgcn_mfma_f32_16x16x32_bf16(a2.v, e2.v, c0, 0, 0, 0);
        c1 = __builtin_amdgcn_mfma_f32_16x16x32_bf16(a1.v, o1u.v, c1, 0, 0, 0);
        c1 = __builtin_amdgcn_mfma_f32_16x16x32_bf16(a2.v, o2u.v, c1, 0, 0, 0);

        // D (col=t -> ch 2t/2t+1, row ko=q*4+r) -> swizzled wf row   [R3-verified]
        const int row = wave * 8 + p;
        #pragma unroll
        for (int r = 0; r < 4; ++r) {
            int ko = q * 4 + r;
            u32 pk = pk2bf(c0[r], c1[r]);
            int unit = ko * 4 + (t >> 2);
            wf[row * 256 + ((unit ^ (row & 7)) << 2) + (t & 3)] = pk;
        }

        // rotate pipeline (stale C-slot values after p>=6 are provably never consumed)
        #pragma unroll
        for (int j = 0; j < 8; ++j) { fbA[j] = fbB[j]; fbB[j] = fbC[j]; }
        d32A = d32B; d33A = d33B; d32B = d32C; d33B = d33C;
        #pragma unroll
        for (int i = 0; i < 4; ++i) { a1A[i] = a1B[i]; a1B[i] = a1C[i]; }
        a2A = a2B; a2B = a2C;
        pnF = pnN; ixF = ix3; ix3 = ixN;
    }
    __syncthreads();

    // -------- Phase B (R4-verified): OUT[16x64] = wf[16x480] @ W[480x64]; 2 col-tiles/wave
    const int wcol0 = (wave * 2 + 0) * 16 + t;
    const int wcol1 = (wave * 2 + 1) * 16 + t;
    f32x4 A0 = {0.f, 0.f, 0.f, 0.f}, A1 = {0.f, 0.f, 0.f, 0.f};
    const u16* wt0 = WT + wcol0 * 480 + q * 8;
    const u16* wt1 = WT + wcol1 * 480 + q * 8;
    #pragma unroll
    for (int ks = 0; ks < KP; ++ks) {
        const int u = ks * 4 + q;
        short8 a   = *(const short8*)&wf[t * 256 + ((u ^ (t & 7)) << 2)];
        short8 bb0 = *(const short8*)(wt0 + ks * 32);
        short8 bb1 = *(const short8*)(wt1 + ks * 32);
        A0 = __builtin_amdgcn_mfma_f32_16x16x32_bf16(a, bb0, A0, 0, 0, 0);
        A1 = __builtin_amdgcn_mfma_f32_16x16x32_bf16(a, bb1, A1, 0, 0, 0);
    }
    const int base = blockIdx.x * PPB;
    #pragma unroll
    for (int r = 0; r < 4; ++r) {
        out[(base + q * 4 + r) * COUT + wcol0] = A0[r];
        out[(base + q * 4 + r) * COUT + wcol1] = A1[r];
    }
}

// Fused stats: 512 blocks compute per-block partials -> Part; the LAST block
// (elected via device-scope counter + threadfence) reduces Part and writes scsh.
__global__ __launch_bounds__(256) void stat_bn(
    const float* __restrict__ out, float* __restrict__ Part, u32* __restrict__ cnt,
    const float* __restrict__ gamma, const float* __restrict__ beta,
    float* __restrict__ scsh)
{
    const int tid = threadIdx.x, lane = tid & 63, wave = tid >> 6;
    const int u = tid & 15;                   // float4 column (channels 4u..4u+3)
    const int pr = tid >> 4;                  // point-row group 0..15
    const float4* O = (const float4*)out + (size_t)blockIdx.x * 4096;  // 256 pts * 16 f4
    float s0 = 0.f, s1 = 0.f, s2 = 0.f, s3 = 0.f;
    float q0 = 0.f, q1 = 0.f, q2 = 0.f, q3 = 0.f;
    #pragma unroll
    for (int it = 0; it < 16; ++it) {
        float4 v = O[(it * 16 + pr) * 16 + u];
        s0 += v.x; q0 = fmaf(v.x, v.x, q0);
        s1 += v.y; q1 = fmaf(v.y, v.y, q1);
        s2 += v.z; q2 = fmaf(v.z, v.z, q2);
        s3 += v.w; q3 = fmaf(v.w, v.w, q3);
    }
    s0 += __shfl_xor(s0, 16, 64); s0 += __shfl_xor(s0, 32, 64);
    s1 += __shfl_xor(s1, 16, 64); s1 += __shfl_xor(s1, 32, 64);
    s2 += __shfl_xor(s2, 16, 64); s2 += __shfl_xor(s2, 32, 64);
    s3 += __shfl_xor(s3, 16, 64); s3 += __shfl_xor(s3, 32, 64);
    q0 += __shfl_xor(q0, 16, 64); q0 += __shfl_xor(q0, 32, 64);
    q1 += __shfl_xor(q1, 16, 64); q1 += __shfl_xor(q1, 32, 64);
    q2 += __shfl_xor(q2, 16, 64); q2 += __shfl_xor(q2, 32, 64);
    q3 += __shfl_xor(q3, 16, 64); q3 += __shfl_xor(q3, 32, 64);
    __shared__ float red[4][16][8];
    if (lane < 16) {
        float* r = red[wave][lane];
        r[0] = s0; r[1] = s1; r[2] = s2; r[3] = s3;
        r[4] = q0; r[5] = q1; r[6] = q2; r[7] = q3;
    }
    __syncthreads();
    if (tid < 128) {                          // tid = ch*2 + (0:sum | 1:sumsq)
        int ch = tid >> 1, su = tid & 1;
        int uu = ch >> 2, c = ch & 3;
        float v = red[0][uu][su * 4 + c] + red[1][uu][su * 4 + c]
                + red[2][uu][su * 4 + c] + red[3][uu][su * 4 + c];
        Part[blockIdx.x * 128 + tid] = v;
    }
    __threadfence();                          // make Part row visible device-wide
    __shared__ int isLast;
    __syncthreads();
    if (tid == 0) isLast = (atomicAdd(cnt, 1u) == (u32)(NSB - 1)) ? 1 : 0;
    __syncthreads();
    if (!isLast) return;

    // -------- final reduction (last block only): Part[512][128] -> scsh
    const float4* P4 = (const float4*)Part;   // 512 rows x 32 float4
    float4 acc = make_float4(0.f, 0.f, 0.f, 0.f);
    #pragma unroll 8
    for (int it = 0; it < 64; ++it) {         // 16384 float4 / 256 threads
        float4 v = P4[it * 256 + tid];        // col4 = tid & 31 (constant per thread)
        acc.x += v.x; acc.y += v.y; acc.z += v.z; acc.w += v.w;
    }
    acc.x += __shfl_xor(acc.x, 32, 64);
    acc.y += __shfl_xor(acc.y, 32, 64);
    acc.z += __shfl_xor(acc.z, 32, 64);
    acc.w += __shfl_xor(acc.w, 32, 64);
    __shared__ float4 red2[4][32];
    if (lane < 32) red2[wave][lane] = acc;
    __syncthreads();
    if (tid < 32) {
        float4 a = red2[0][tid], b = red2[1][tid], c4 = red2[2][tid], d = red2[3][tid];
        // col4 layout (tid=ch*2+su encoding): (s_{2c}, q_{2c}, s_{2c+1}, q_{2c+1})
        float sA = a.x + b.x + c4.x + d.x;
        float qA = a.y + b.y + c4.y + d.y;
        float sB = a.z + b.z + c4.z + d.z;
        float qB = a.w + b.w + c4.w + d.w;
        const int ch0 = tid * 2, ch1 = tid * 2 + 1;
        float m0 = sA * (1.0f / NPTS), v0 = qA * (1.0f / NPTS) - m0 * m0;
        float m1 = sB * (1.0f / NPTS), v1 = qB * (1.0f / NPTS) - m1 * m1;
        float sc0 = gamma[ch0] * rsqrtf(v0 + BN_EPS);
        float sc1 = gamma[ch1] * rsqrtf(v1 + BN_EPS);
        scsh[ch0] = sc0; scsh[64 + ch0] = beta[ch0] - m0 * sc0;
        scsh[ch1] = sc1; scsh[64 + ch1] = beta[ch1] - m1 * sc1;
    }
}

__global__ __launch_bounds__(256) void bn_apply(
    float* __restrict__ out, const float* __restrict__ scsh)
{
    __shared__ float sc[64], sh[64];
    const int tid = threadIdx.x;
    if (tid < 64) { sc[tid] = scsh[tid]; sh[tid] = scsh[64 + tid]; }
    __syncthreads();
    const int gid = blockIdx.x * 256 + tid;          // 4 f32 per thread
    float4 v = ((const float4*)out)[gid];
    const int c0 = (gid * 4) & 63;
    float y0 = fmaf(v.x, sc[c0 + 0], sh[c0 + 0]);
    float y1 = fmaf(v.y, sc[c0 + 1], sh[c0 + 1]);
    float y2 = fmaf(v.z, sc[c0 + 2], sh[c0 + 2]);
    float y3 = fmaf(v.w, sc[c0 + 3], sh[c0 + 3]);
    float4 w;
    w.x = fmaxf(y0, NEG_SLOPE * y0);
    w.y = fmaxf(y1, NEG_SLOPE * y1);
    w.z = fmaxf(y2, NEG_SLOPE * y2);
    w.w = fmaxf(y3, NEG_SLOPE * y3);
    ((float4*)out)[gid] = w;
}

extern "C" void kernel_launch(void* const* d_in, const int* in_sizes, int n_in,
                              void* d_out, int out_size, void* d_ws, size_t ws_size,
                              hipStream_t stream) {
    (void)in_sizes; (void)n_in; (void)out_size; (void)ws_size;
    const float* xyz   = (const float*)d_in[0];
    const float* feats = (const float*)d_in[1];
    const int*   nbr   = (const int*)d_in[2];
    const float* Wg    = (const float*)d_in[3];
    const float* kpts  = (const float*)d_in[4];
    const float* gamma = (const float*)d_in[5];
    const float* beta  = (const float*)d_in[6];
    float* out = (float*)d_out;
    char* ws = (char*)d_ws;
    u16*    WT   = (u16*)(ws + WS_WT);
    float*  scsh = (float*)(ws + WS_SCSH);
    u32*    cnt  = (u32*)(ws + WS_CNT);
    float*  Part = (float*)(ws + WS_PART);
    float4* XY   = (float4*)(ws + WS_XY);
    u32*    FBu  = (u32*)(ws + WS_FB);

    prep<<<dim3(2682), dim3(256), 0, stream>>>(Wg, feats, xyz, WT, XY, (uint4*)FBu, cnt);
    kpconv_conv<<<dim3(NBLK), dim3(128), 0, stream>>>(xyz, nbr, XY, FBu, WT, kpts, out);
    stat_bn<<<dim3(NSB), dim3(256), 0, stream>>>(out, Part, cnt, gamma, beta, scsh);
    bn_apply<<<dim3((NPTS * COUT) / (256 * 4)), dim3(256), 0, stream>>>(out, scsh);
}

// Round 10
// 211.248 us; speedup vs baseline: 1.1736x; 1.1736x over previous
//
#include <hip/hip_runtime.h>

#define NPTS 131072
#define MNBR 34
#define KP 15
#define CIN 32
#define COUT 64
#define INV_INFL 25.0f          // 1 / POINT_INFLUENCE(0.04)
#define BN_EPS 1e-5f
#define NEG_SLOPE 0.2f
#define PPB 16                  // points per block (2 waves x 8)
#define NBLK (NPTS / PPB)       // 8192 conv blocks
#define NSB 512                 // stat blocks (256 points each)

typedef unsigned short u16;
typedef unsigned int u32;
typedef unsigned long long u64;
typedef short short8 __attribute__((ext_vector_type(8)));   // 8 bf16 (4 VGPRs)
typedef float f32x4 __attribute__((ext_vector_type(4)));

static __device__ __forceinline__ u16 f2bf(float f) {       // RNE
    u32 x = __float_as_uint(f);
    x += 0x7fffu + ((x >> 16) & 1u);
    return (u16)(x >> 16);
}
static __device__ __forceinline__ u32 pk2bf(float lo, float hi) {  // round-half-up pack
    u32 a = __float_as_uint(lo) + 0x8000u;
    u32 b = __float_as_uint(hi) + 0x8000u;
    return (a >> 16) | (b & 0xffff0000u);
}
static __device__ __forceinline__ u32 pkbf(float lo, float hi) {   // RNE pack (FB table)
    return (u32)f2bf(lo) | ((u32)f2bf(hi) << 16);
}

// ws layout (bytes) — total 10.38 MB (unchanged, proven footprint)
#define WS_WT   0u              // u16[64*480]          = 61440
#define WS_SCSH 65536u          // f32[128]
#define WS_PART 131072u         // f32[512*128]         = 262144 (block stat partials)
#define WS_XY   393216u         // float4[NPTS+1]       = 2097168 (xyz padded + shadow row)
#define WS_FB   2490624u        // u16[(NPTS+1)*32]     = 8388672 bf16 feats + zero shadow row

// prep: WT transpose, XY padded xyz table, FB bf16 table (uint4 fill)
__global__ __launch_bounds__(256) void prep(const float* __restrict__ Wg,
                                            const float* __restrict__ feats,
                                            const float* __restrict__ xyz,
                                            u16* __restrict__ WT, float4* __restrict__ XY,
                                            uint4* __restrict__ FB4) {
    int b = blockIdx.x;
    if (b < 120) {
        int i2 = b * 256 + threadIdx.x;          // < 30720
        WT[(i2 & 63) * 480 + (i2 >> 6)] = f2bf(Wg[i2]);
    } else if (b < 633) {
        int r = (b - 120) * 256 + threadIdx.x;
        if (r <= NPTS) {
            float4 v;
            if (r < NPTS) v = make_float4(xyz[3 * r], xyz[3 * r + 1], xyz[3 * r + 2], 0.f);
            else          v = make_float4(1e6f, 1e6f, 1e6f, 0.f);   // shadow -> w = 0
            XY[r] = v;
        }
    } else {
        // FB fill: one uint4 (8 bf16) per thread from two float4 loads.
        // real data: NPTS*CIN/8 = 524288 uint4; +4 uint4 shadow-row zeros.
        int g4 = (b - 633) * 256 + threadIdx.x;
        if (g4 < 524292) {
            uint4 v = make_uint4(0u, 0u, 0u, 0u);
            if (g4 < 524288) {
                const float4* F4 = (const float4*)feats;
                float4 f0 = F4[g4 * 2], f1 = F4[g4 * 2 + 1];
                v.x = pkbf(f0.x, f0.y); v.y = pkbf(f0.z, f0.w);
                v.z = pkbf(f1.x, f1.y); v.w = pkbf(f1.z, f1.w);
            }
            FB4[g4] = v;
        }
    }
}

__global__ __launch_bounds__(128, 3) void kpconv_conv(
    const float* __restrict__ xyz, const int* __restrict__ nbr,
    const float4* __restrict__ XY, const u32* __restrict__ FBu,
    const u16* __restrict__ WT, const float* __restrict__ kpts,
    float* __restrict__ out)
{
    // wf: 16 rows x 512 bf16; 16B-unit u of row r at phys (u ^ (r&7))   [R3-verified]
    __shared__ u32 wf[PPB * 256];            // 16 KB
    // offs: per-wave SINGLE-buffer (ox,oy,oz,|o|^2); slot m at phys
    // (m&~7)|((m^(m>>3))&7). Written+read within the same stage step.
    __shared__ float4 offs4[2][64];          // 2 KB     (total 18 KB)

    const int tid = threadIdx.x, lane = tid & 63, wave = tid >> 6;
    const int q = lane >> 4, t = lane & 15;
    const int pbase = blockIdx.x * PPB + wave * 8;

    // per-lane kernel-point constants (k == t only): d^2 = (o.a_t + c_t) + |o|^2
    float axt = 0.f, ayt = 0.f, azt = 0.f, ckt = 1e30f;   // t==15 pad -> w=0
    if (t < KP) {
        float kx = kpts[3 * t], ky = kpts[3 * t + 1], kz = kpts[3 * t + 2];
        axt = -2.f * kx; ayt = -2.f * ky; azt = -2.f * kz;
        ckt = fmaf(kx, kx, fmaf(ky, ky, kz * kz));
    }
    const int wslot = (lane & ~7) | ((lane ^ (lane >> 3)) & 7);
    const int sl = q * 8;                     // shuffle source base lane

    auto ldnbr = [&](int pp) {
        int v = NPTS;
        if (lane < MNBR) v = nbr[(size_t)(pbase + pp) * MNBR + lane];
        if ((u32)v > (u32)NPTS) v = NPTS;
        return v;
    };

    // hoisted wave-uniform query positions (compile-time indexed -> regs)
    float qxv[8], qyv[8], qzv[8];
    #pragma unroll
    for (int p = 0; p < 8; ++p) {
        const int n1 = pbase + p;
        qxv[p] = xyz[3 * n1]; qyv[p] = xyz[3 * n1 + 1]; qzv[p] = xyz[3 * n1 + 2];
    }

    // 3-deep pipeline: A = current point, B = +1, C = staged +2.
    // Weights computed AT STAGE TIME; per-row ballot of (w>0) gives an EXACT
    // skip mask (rows with all-zero weights contribute exactly 0; fb zero-init).
    u32 fbA[8] = {0,0,0,0,0,0,0,0};
    u32 fbB[8] = {0,0,0,0,0,0,0,0};
    u32 fbC[8] = {0,0,0,0,0,0,0,0};
    u32 d32A = 0, d33A = 0, d32B = 0, d33B = 0, d32C = 0, d33C = 0;
    u32 a1A[4], a1B[4], a1C[4];
    u32 a2A = 0, a2B = 0, a2C = 0;

    #define STAGE(P, ixP, pnP, a1X, a2X, fbX, d32X, d33X)                         \
    {                                                                              \
        float ox = (pnP).x - qxv[P], oy = (pnP).y - qyv[P], oz = (pnP).z - qzv[P]; \
        float ow = fmaf(ox, ox, fmaf(oy, oy, oz * oz));                            \
        offs4[wave][wslot] = make_float4(ox, oy, oz, ow);                          \
        const float4* ob = &offs4[wave][0];                                        \
        float wjs[8];                                                              \
        _Pragma("unroll")                                                          \
        for (int j = 0; j < 8; ++j) {                                              \
            float4 o = ob[q * 8 + (j ^ q)];    /* logical row q*8+j */             \
            float d2 = fmaf(o.x, axt, fmaf(o.y, ayt, fmaf(o.z, azt, ckt))) + o.w;  \
            float dd = __builtin_amdgcn_sqrtf(d2);                                 \
            wjs[j] = fmaxf(0.f, fmaf(dd, -INV_INFL, 1.f));                         \
        }                                                                          \
        _Pragma("unroll")                                                          \
        for (int i = 0; i < 4; ++i) a1X[i] = pk2bf(wjs[2 * i], wjs[2 * i + 1]);    \
        float4 oA = ob[36], oB = ob[37];       /* logical rows 32,33 */            \
        float dA = __builtin_amdgcn_sqrtf(fmaf(oA.x, axt, fmaf(oA.y, ayt, fmaf(oA.z, azt, ckt))) + oA.w); \
        float dB = __builtin_amdgcn_sqrtf(fmaf(oB.x, axt, fmaf(oB.y, ayt, fmaf(oB.z, azt, ckt))) + oB.w); \
        float wA = fmaxf(0.f, fmaf(dA, -INV_INFL, 1.f));                           \
        float wB = fmaxf(0.f, fmaf(dB, -INV_INFL, 1.f));                           \
        a2X = (q == 0) ? pk2bf(wA, wB) : 0u;                                       \
        _Pragma("unroll")                                                          \
        for (int j = 0; j < 8; ++j) {                                              \
            u64 bj = __ballot(wjs[j] > 0.f);   /* row q*8+j votes in [q*16,+16) */ \
            u32 half = (q & 2) ? (u32)(bj >> 32) : (u32)bj;                        \
            u32 m16 = (half >> ((q & 1) * 16)) & 0xffffu;                          \
            u32 r = (u32)__shfl((ixP), sl + j, 64);                                \
            if (m16) fbX[j] = FBu[(size_t)r * 16 + t];                             \
        }                                                                          \
        u64 b32 = __ballot(wA > 0.f);                                              \
        u64 b33 = __ballot(wB > 0.f);                                              \
        int r32 = __builtin_amdgcn_readlane((ixP), 32);                            \
        int r33 = __builtin_amdgcn_readlane((ixP), 33);                            \
        if (b32) d32X = FBu[(size_t)r32 * 16 + t];                                 \
        if (b33) d33X = FBu[(size_t)r33 * 16 + t];                                 \
    }

    // ---------------- prologue: nbr 0..3; XY 0..2; stage points 0 and 1
    int ix0 = ldnbr(0);
    int ix1 = ldnbr(1);
    int ixF = ldnbr(2);                       // stage source for p+2
    int ix3 = ldnbr(3);                       // XY load source for p+3
    float4 pn0 = XY[ix0];
    float4 pn1 = XY[ix1];
    float4 pnF = XY[ixF];

    STAGE(0, ix0, pn0, a1A, a2A, fbA, d32A, d33A);
    STAGE(1, ix1, pn1, a1B, a2B, fbB, d32B, d33B);

    // FULLY UNROLLED main loop.
    #pragma unroll
    for (int p = 0; p < 8; ++p) {
        // (a) nbr for p+4
        int ixN = NPTS;
        if (p < 4) ixN = ldnbr(p + 4);
        // (b) neighbor XY rows for p+3
        float4 pnN = make_float4(1e6f, 1e6f, 1e6f, 0.f);
        if (p < 5) pnN = XY[ix3];
        // (c) stage point p+2 (weights + exact-skip predicated gathers)
        if (p < 6) {
            STAGE(p + 2, ixF, pnF, a1C, a2C, fbC, d32C, d33C);
        }

        // (e) compute point p — everything from carried registers
        union { short8 v; u32 d[4]; } a1, a2, e1, o1u, e2, o2u;
        a1.d[0] = a1A[0]; a1.d[1] = a1A[1]; a1.d[2] = a1A[2]; a1.d[3] = a1A[3];
        a2.d[0] = a2A; a2.d[1] = 0; a2.d[2] = 0; a2.d[3] = 0;
        #pragma unroll
        for (int i = 0; i < 4; ++i) {                    // even/odd channel split
            u32 aa = fbA[2 * i], bb2 = fbA[2 * i + 1];
            e1.d[i] = (aa & 0xffffu) | (bb2 << 16);
            o1u.d[i] = (aa >> 16) | (bb2 & 0xffff0000u);
        }
        {
            u32 lo = (d32A & 0xffffu) | (d33A << 16);
            u32 hi = (d32A >> 16) | (d33A & 0xffff0000u);
            e2.d[0] = (q == 0) ? lo : 0u;  e2.d[1] = 0; e2.d[2] = 0; e2.d[3] = 0;
            o2u.d[0] = (q == 0) ? hi : 0u; o2u.d[1] = 0; o2u.d[2] = 0; o2u.d[3] = 0;
        }
        f32x4 c0 = {0.f, 0.f, 0.f, 0.f}, c1 = {0.f, 0.f, 0.f, 0.f};
        c0 = __builtin_amdgcn_mfma_f32_16x16x32_bf16(a1.v, e1.v, c0, 0, 0, 0);
        c0 = __builtin_amdgcn_mfma_f32_16x16x32_bf16(a2.v, e2.v, c0, 0, 0, 0);
        c1 = __builtin_amdgcn_mfma_f32_16x16x32_bf16(a1.v, o1u.v, c1, 0, 0, 0);
        c1 = __builtin_amdgcn_mfma_f32_16x16x32_bf16(a2.v, o2u.v, c1, 0, 0, 0);

        // D (col=t -> ch 2t/2t+1, row ko=q*4+r) -> swizzled wf row   [R3-verified]
        const int row = wave * 8 + p;
        #pragma unroll
        for (int r = 0; r < 4; ++r) {
            int ko = q * 4 + r;
            u32 pk = pk2bf(c0[r], c1[r]);
            int unit = ko * 4 + (t >> 2);
            wf[row * 256 + ((unit ^ (row & 7)) << 2) + (t & 3)] = pk;
        }

        // rotate pipeline (stale C-slot values after p>=6 are provably never consumed)
        #pragma unroll
        for (int j = 0; j < 8; ++j) { fbA[j] = fbB[j]; fbB[j] = fbC[j]; }
        d32A = d32B; d33A = d33B; d32B = d32C; d33B = d33C;
        #pragma unroll
        for (int i = 0; i < 4; ++i) { a1A[i] = a1B[i]; a1B[i] = a1C[i]; }
        a2A = a2B; a2B = a2C;
        pnF = pnN; ixF = ix3; ix3 = ixN;
    }
    __syncthreads();

    // -------- Phase B (R4-verified): OUT[16x64] = wf[16x480] @ W[480x64]; 2 col-tiles/wave
    const int wcol0 = (wave * 2 + 0) * 16 + t;
    const int wcol1 = (wave * 2 + 1) * 16 + t;
    f32x4 A0 = {0.f, 0.f, 0.f, 0.f}, A1 = {0.f, 0.f, 0.f, 0.f};
    const u16* wt0 = WT + wcol0 * 480 + q * 8;
    const u16* wt1 = WT + wcol1 * 480 + q * 8;
    #pragma unroll
    for (int ks = 0; ks < KP; ++ks) {
        const int u = ks * 4 + q;
        short8 a   = *(const short8*)&wf[t * 256 + ((u ^ (t & 7)) << 2)];
        short8 bb0 = *(const short8*)(wt0 + ks * 32);
        short8 bb1 = *(const short8*)(wt1 + ks * 32);
        A0 = __builtin_amdgcn_mfma_f32_16x16x32_bf16(a, bb0, A0, 0, 0, 0);
        A1 = __builtin_amdgcn_mfma_f32_16x16x32_bf16(a, bb1, A1, 0, 0, 0);
    }
    const int base = blockIdx.x * PPB;
    #pragma unroll
    for (int r = 0; r < 4; ++r) {
        out[(base + q * 4 + r) * COUT + wcol0] = A0[r];
        out[(base + q * 4 + r) * COUT + wcol1] = A1[r];
    }
}

// 512 blocks x 256 points: per-block channel partials (sum, sumsq) -> Part[512][128]
__global__ __launch_bounds__(256) void stat_partial(const float* __restrict__ out,
                                                    float* __restrict__ Part)
{
    const int tid = threadIdx.x, lane = tid & 63, wave = tid >> 6;
    const int u = tid & 15;                   // float4 column (channels 4u..4u+3)
    const int pr = tid >> 4;                  // point-row group 0..15
    const float4* O = (const float4*)out + (size_t)blockIdx.x * 4096;  // 256 pts * 16 f4
    float s0 = 0.f, s1 = 0.f, s2 = 0.f, s3 = 0.f;
    float q0 = 0.f, q1 = 0.f, q2 = 0.f, q3 = 0.f;
    #pragma unroll
    for (int it = 0; it < 16; ++it) {
        float4 v = O[(it * 16 + pr) * 16 + u];
        s0 += v.x; q0 = fmaf(v.x, v.x, q0);
        s1 += v.y; q1 = fmaf(v.y, v.y, q1);
        s2 += v.z; q2 = fmaf(v.z, v.z, q2);
        s3 += v.w; q3 = fmaf(v.w, v.w, q3);
    }
    s0 += __shfl_xor(s0, 16, 64); s0 += __shfl_xor(s0, 32, 64);
    s1 += __shfl_xor(s1, 16, 64); s1 += __shfl_xor(s1, 32, 64);
    s2 += __shfl_xor(s2, 16, 64); s2 += __shfl_xor(s2, 32, 64);
    s3 += __shfl_xor(s3, 16, 64); s3 += __shfl_xor(s3, 32, 64);
    q0 += __shfl_xor(q0, 16, 64); q0 += __shfl_xor(q0, 32, 64);
    q1 += __shfl_xor(q1, 16, 64); q1 += __shfl_xor(q1, 32, 64);
    q2 += __shfl_xor(q2, 16, 64); q2 += __shfl_xor(q2, 32, 64);
    q3 += __shfl_xor(q3, 16, 64); q3 += __shfl_xor(q3, 32, 64);
    __shared__ float red[4][16][8];
    if (lane < 16) {
        float* r = red[wave][lane];
        r[0] = s0; r[1] = s1; r[2] = s2; r[3] = s3;
        r[4] = q0; r[5] = q1; r[6] = q2; r[7] = q3;
    }
    __syncthreads();
    if (tid < 128) {                          // tid = ch*2 + (0:sum | 1:sumsq)
        int ch = tid >> 1, su = tid & 1;
        int uu = ch >> 2, c = ch & 3;
        float v = red[0][uu][su * 4 + c] + red[1][uu][su * 4 + c]
                + red[2][uu][su * 4 + c] + red[3][uu][su * 4 + c];
        Part[blockIdx.x * 128 + tid] = v;
    }
}

// 64 blocks: block = channel; reduce Part columns -> scale/shift
__global__ __launch_bounds__(256) void bn_reduce(
    const float* __restrict__ Part,
    const float* __restrict__ gamma, const float* __restrict__ beta,
    float* __restrict__ scsh)
{
    const int ch = blockIdx.x;
    const int tid = threadIdx.x;
    float s = 0.f, qq = 0.f;
    for (int b = tid; b < NSB; b += 256) {
        s  += Part[b * 128 + ch * 2];
        qq += Part[b * 128 + ch * 2 + 1];
    }
    #pragma unroll
    for (int off = 1; off < 64; off <<= 1) {
        s += __shfl_xor(s, off, 64); qq += __shfl_xor(qq, off, 64);
    }
    __shared__ float red[8];
    const int w = tid >> 6;
    if ((tid & 63) == 0) { red[w * 2] = s; red[w * 2 + 1] = qq; }
    __syncthreads();
    if (tid == 0) {
        s  = red[0] + red[2] + red[4] + red[6];
        qq = red[1] + red[3] + red[5] + red[7];
        float mean = s * (1.0f / NPTS);
        float var  = qq * (1.0f / NPTS) - mean * mean;
        float sc = gamma[ch] * rsqrtf(var + BN_EPS);
        scsh[ch] = sc;
        scsh[64 + ch] = beta[ch] - mean * sc;
    }
}

__global__ __launch_bounds__(256) void bn_apply(
    float* __restrict__ out, const float* __restrict__ scsh)
{
    __shared__ float sc[64], sh[64];
    const int tid = threadIdx.x;
    if (tid < 64) { sc[tid] = scsh[tid]; sh[tid] = scsh[64 + tid]; }
    __syncthreads();
    const int gid = blockIdx.x * 256 + tid;          // 4 f32 per thread
    float4 v = ((const float4*)out)[gid];
    const int c0 = (gid * 4) & 63;
    float y0 = fmaf(v.x, sc[c0 + 0], sh[c0 + 0]);
    float y1 = fmaf(v.y, sc[c0 + 1], sh[c0 + 1]);
    float y2 = fmaf(v.z, sc[c0 + 2], sh[c0 + 2]);
    float y3 = fmaf(v.w, sc[c0 + 3], sh[c0 + 3]);
    float4 w;
    w.x = fmaxf(y0, NEG_SLOPE * y0);
    w.y = fmaxf(y1, NEG_SLOPE * y1);
    w.z = fmaxf(y2, NEG_SLOPE * y2);
    w.w = fmaxf(y3, NEG_SLOPE * y3);
    ((float4*)out)[gid] = w;
}

extern "C" void kernel_launch(void* const* d_in, const int* in_sizes, int n_in,
                              void* d_out, int out_size, void* d_ws, size_t ws_size,
                              hipStream_t stream) {
    (void)in_sizes; (void)n_in; (void)out_size; (void)ws_size;
    const float* xyz   = (const float*)d_in[0];
    const float* feats = (const float*)d_in[1];
    const int*   nbr   = (const int*)d_in[2];
    const float* Wg    = (const float*)d_in[3];
    const float* kpts  = (const float*)d_in[4];
    const float* gamma = (const float*)d_in[5];
    const float* beta  = (const float*)d_in[6];
    float* out = (float*)d_out;
    char* ws = (char*)d_ws;
    u16*    WT   = (u16*)(ws + WS_WT);
    float*  scsh = (float*)(ws + WS_SCSH);
    float*  Part = (float*)(ws + WS_PART);
    float4* XY   = (float4*)(ws + WS_XY);
    u32*    FBu  = (u32*)(ws + WS_FB);

    prep<<<dim3(2682), dim3(256), 0, stream>>>(Wg, feats, xyz, WT, XY, (uint4*)FBu);
    kpconv_conv<<<dim3(NBLK), dim3(128), 0, stream>>>(xyz, nbr, XY, FBu, WT, kpts, out);
    stat_partial<<<dim3(NSB), dim3(256), 0, stream>>>(out, Part);
    bn_reduce<<<dim3(64), dim3(256), 0, stream>>>(Part, gamma, beta, scsh);
    bn_apply<<<dim3((NPTS * COUT) / (256 * 4)), dim3(256), 0, stream>>>(out, scsh);
}